// Round 2
// baseline (2498.432 us; speedup 1.0000x reference)
//
#include <hip/hip_runtime.h>
#include <hip/hip_bf16.h>

// Performer (FAVOR+) attention forward.
// B=2, N=4096, H=16, D=64, M=266 features, DIM=1024.
// I/O: fp32 (reference dtype). bf16-grade tolerance (2% of absmax) permits
// bf16 internal storage of Q/K/V/attn intermediates.

#define B_   2
#define N_   4096
#define H_   16
#define D_   64
#define M_   266
#define DIM_ 1024
#define RT_  8192   // B_*N_
#define BH_  32     // B_*H_
#define DDS  273    // LDS stride for 266-wide dd rows (odd -> conflict-free)

__device__ __forceinline__ float  b2f(__hip_bfloat16 x){ return __bfloat162float(x); }
__device__ __forceinline__ __hip_bfloat16 f2b(float x){ return __float2bfloat16(x); }

constexpr float NORMC  = 0.35355339059327379f;  // 64^-0.25
constexpr float RATIOC = 0.06131393f;           // 266^-0.5
constexpr float DIAGC  = 0.0625f;               // 0.5 * 64^-0.5
constexpr float EPSC   = 1e-4f;

// order-preserving float<->uint encode for atomicMax over signed floats
__device__ __forceinline__ unsigned encf(float x){
    unsigned b = __float_as_uint(x);
    return (b & 0x80000000u) ? ~b : (b | 0x80000000u);
}
__device__ __forceinline__ float decf(unsigned u){
    unsigned b = (u & 0x80000000u) ? (u ^ 0x80000000u) : ~u;
    return __uint_as_float(b);
}

// typed helpers: load-4-as-float4, store-float
__device__ __forceinline__ float4 ld4f(const float* p){ return *(const float4*)p; }
__device__ __forceinline__ float4 ld4f(const __hip_bfloat16* p){
    const ushort4 u = *(const ushort4*)p;
    return make_float4(__uint_as_float((unsigned)u.x << 16),
                       __uint_as_float((unsigned)u.y << 16),
                       __uint_as_float((unsigned)u.z << 16),
                       __uint_as_float((unsigned)u.w << 16));
}
__device__ __forceinline__ void stf(float* p, float v){ *p = v; }
__device__ __forceinline__ void stf(__hip_bfloat16* p, float v){ *p = f2b(v); }

// ---------------------------------------------------------------------------
// C[r,c] = sum_k A[r,k]*Bw[c,k] (+bias[c]). A: fp32 or bf16; Bw,bias fp32;
// C: fp32 or bf16. 64x64 tile, BK=16, 256 threads, 4x4 micro. Optionally
// emits per-head diag[row*16 + head] = 0.0625 * sum_c C[r,c]^2
// (c-tile == one head, valid because 64 cols == DIM_HEAD).
// ---------------------------------------------------------------------------
template<bool DIAG, bool BIAS, typename TA, typename TC>
__launch_bounds__(256)
__global__ void gemm_tn(const TA* __restrict__ A,
                        const float* __restrict__ Bw,
                        const float* __restrict__ bias,
                        TC* __restrict__ Cout,
                        float* __restrict__ diag)
{
    __shared__ float As[16][64];
    __shared__ float Bs[16][64];
    __shared__ float red[16][64];

    const int tid = threadIdx.x;
    const int tx = tid & 15, ty = tid >> 4;
    const int c0 = blockIdx.x * 64, r0 = blockIdx.y * 64;
    const int lr = tid >> 2;          // 0..63
    const int lk = (tid & 3) * 4;     // 0,4,8,12

    float acc[4][4] = {};

    for (int kk = 0; kk < DIM_; kk += 16) {
        const float4 a4 = ld4f(A  + (size_t)(r0 + lr) * DIM_ + kk + lk);
        const float4 b4 = ld4f(Bw + (size_t)(c0 + lr) * DIM_ + kk + lk);
        As[lk + 0][lr] = a4.x; As[lk + 1][lr] = a4.y;
        As[lk + 2][lr] = a4.z; As[lk + 3][lr] = a4.w;
        Bs[lk + 0][lr] = b4.x; Bs[lk + 1][lr] = b4.y;
        Bs[lk + 2][lr] = b4.z; Bs[lk + 3][lr] = b4.w;
        __syncthreads();
        #pragma unroll
        for (int k = 0; k < 16; ++k) {
            const float4 av = *(const float4*)&As[k][ty * 4];
            const float4 bv = *(const float4*)&Bs[k][tx * 4];
            const float a4v[4] = {av.x, av.y, av.z, av.w};
            const float b4v[4] = {bv.x, bv.y, bv.z, bv.w};
            #pragma unroll
            for (int i = 0; i < 4; ++i)
                #pragma unroll
                for (int j = 0; j < 4; ++j) acc[i][j] += a4v[i] * b4v[j];
        }
        __syncthreads();
    }

    float bb[4] = {0.f, 0.f, 0.f, 0.f};
    if (BIAS) {
        #pragma unroll
        for (int j = 0; j < 4; ++j) bb[j] = bias[c0 + tx * 4 + j];
    }
    #pragma unroll
    for (int i = 0; i < 4; ++i) {
        const size_t row = (size_t)(r0 + ty * 4 + i);
        #pragma unroll
        for (int j = 0; j < 4; ++j)
            stf(&Cout[row * DIM_ + c0 + tx * 4 + j], acc[i][j] + bb[j]);
    }

    if (DIAG) {
        #pragma unroll
        for (int i = 0; i < 4; ++i) {
            float s = 0.f;
            #pragma unroll
            for (int j = 0; j < 4; ++j) s += acc[i][j] * acc[i][j];
            red[tx][ty * 4 + i] = s;
        }
        __syncthreads();
        if (tid < 64) {
            float s = 0.f;
            #pragma unroll
            for (int x = 0; x < 16; ++x) s += red[x][tid];
            diag[(size_t)(r0 + tid) * H_ + blockIdx.x] = DIAGC * s;
        }
    }
}

// ---------------------------------------------------------------------------
// Global max over (n,m) of kdash per (b,h). 320 threads, thread t owns m=t,
// proj row (x NORMC) held in 64 unrolled VGPRs. Grid (8 n-chunks, 32 bh).
// ---------------------------------------------------------------------------
__launch_bounds__(320)
__global__ void kmax_kernel(const __hip_bfloat16* __restrict__ Kb,
                            const float* __restrict__ proj,
                            unsigned* __restrict__ kmaxb)
{
    __shared__ float krow[4][64];
    __shared__ float wred[5];
    const int tid = threadIdx.x;
    const int bh = blockIdx.y, b = bh >> 4, h = bh & 15;
    const int n0 = blockIdx.x * 512;

    float pr[64];
    if (tid < M_) {
        #pragma unroll
        for (int d = 0; d < 64; ++d) pr[d] = NORMC * proj[tid * 64 + d];
    }
    float lmax = -3.4e38f;
    const size_t base = ((size_t)b * N_ + n0) * DIM_ + h * 64;

    for (int n = 0; n < 512; n += 4) {
        __syncthreads();
        if (tid < 256) {
            const int g = tid >> 6, d = tid & 63;
            krow[g][d] = b2f(Kb[base + (size_t)(n + g) * DIM_ + d]);
        }
        __syncthreads();
        if (tid < M_) {
            #pragma unroll
            for (int g = 0; g < 4; ++g) {
                const float4* k4 = (const float4*)krow[g];
                float dd = 0.f;
                #pragma unroll
                for (int i = 0; i < 16; ++i) {
                    const float4 kv = k4[i];
                    dd += kv.x * pr[4*i] + kv.y * pr[4*i+1] + kv.z * pr[4*i+2] + kv.w * pr[4*i+3];
                }
                lmax = fmaxf(lmax, dd);
            }
        }
    }
    #pragma unroll
    for (int o = 32; o > 0; o >>= 1) lmax = fmaxf(lmax, __shfl_down(lmax, o, 64));
    if ((tid & 63) == 0) wred[tid >> 6] = lmax;
    __syncthreads();
    if (tid == 0) {
        float m = wred[0];
        #pragma unroll
        for (int w = 1; w < 5; ++w) m = fmaxf(m, wred[w]);
        atomicMax(&kmaxb[bh], encf(m));
    }
}

// ---------------------------------------------------------------------------
// context[bh][m][e] += sum_n kp[n,m]*v[n,e];  kcs[bh][m] += sum_n kp[n,m].
// Thread t owns m=t: 64-reg proj row + 64-reg accumulator; atomicAdd at end.
// ---------------------------------------------------------------------------
__launch_bounds__(320)
__global__ void kctx_kernel(const __hip_bfloat16* __restrict__ Kb,
                            const __hip_bfloat16* __restrict__ Vb,
                            const float* __restrict__ proj,
                            const float* __restrict__ diagK,
                            const unsigned* __restrict__ kmaxb,
                            float* __restrict__ ctx,
                            float* __restrict__ kcs)
{
    __shared__ float krow[4][64];
    __shared__ float vrow[4][64];
    __shared__ float dg[4];
    const int tid = threadIdx.x;
    const int bh = blockIdx.y, b = bh >> 4, h = bh & 15;
    const int n0 = blockIdx.x * 512;

    float pr[64];
    if (tid < M_) {
        #pragma unroll
        for (int d = 0; d < 64; ++d) pr[d] = NORMC * proj[tid * 64 + d];
    }
    const float kmax = decf(kmaxb[bh]);
    float acc[64] = {};
    float accs = 0.f;
    const size_t base = ((size_t)b * N_ + n0) * DIM_ + h * 64;

    for (int n = 0; n < 512; n += 4) {
        __syncthreads();
        if (tid < 256) {
            const int g = tid >> 6, d = tid & 63;
            const size_t ro = base + (size_t)(n + g) * DIM_;
            krow[g][d] = b2f(Kb[ro + d]);
            vrow[g][d] = b2f(Vb[ro + d]);
        }
        if (tid >= 256 && tid < 260) {
            const int g = tid - 256;
            dg[g] = diagK[((size_t)b * N_ + n0 + n + g) * H_ + h];
        }
        __syncthreads();
        if (tid < M_) {
            float kp[4];
            #pragma unroll
            for (int g = 0; g < 4; ++g) {
                const float4* k4 = (const float4*)krow[g];
                float dd = 0.f;
                #pragma unroll
                for (int i = 0; i < 16; ++i) {
                    const float4 kv = k4[i];
                    dd += kv.x * pr[4*i] + kv.y * pr[4*i+1] + kv.z * pr[4*i+2] + kv.w * pr[4*i+3];
                }
                kp[g] = RATIOC * (__expf(fminf(dd - dg[g] - kmax, 0.f)) + EPSC);
                accs += kp[g];
            }
            #pragma unroll
            for (int i = 0; i < 16; ++i) {
                const float4 v0 = ((const float4*)vrow[0])[i];
                const float4 v1 = ((const float4*)vrow[1])[i];
                const float4 v2 = ((const float4*)vrow[2])[i];
                const float4 v3 = ((const float4*)vrow[3])[i];
                acc[4*i+0] += kp[0]*v0.x + kp[1]*v1.x + kp[2]*v2.x + kp[3]*v3.x;
                acc[4*i+1] += kp[0]*v0.y + kp[1]*v1.y + kp[2]*v2.y + kp[3]*v3.y;
                acc[4*i+2] += kp[0]*v0.z + kp[1]*v1.z + kp[2]*v2.z + kp[3]*v3.z;
                acc[4*i+3] += kp[0]*v0.w + kp[1]*v1.w + kp[2]*v2.w + kp[3]*v3.w;
            }
        }
    }
    if (tid < M_) {
        float* cp = ctx + ((size_t)bh * M_ + tid) * 64;
        #pragma unroll
        for (int e = 0; e < 64; ++e) atomicAdd(&cp[e], acc[e]);
        atomicAdd(&kcs[(size_t)bh * M_ + tid], accs);
    }
}

// ---------------------------------------------------------------------------
// Fused Q path: per 32-row tile -> dd (LDS fp32) -> rowmax -> qp=exp(...) ->
// den=qp.kcs -> out = (qp @ context) * (1/den) -> attn buffer (bf16).
// Grid (32 n-blocks of 128 rows, 32 bh), 320 threads.
// ---------------------------------------------------------------------------
__launch_bounds__(320)
__global__ void qout_kernel(const __hip_bfloat16* __restrict__ Qb,
                            const float* __restrict__ proj,
                            const float* __restrict__ diagQ,
                            const float* __restrict__ ctx,
                            const float* __restrict__ kcs,
                            __hip_bfloat16* __restrict__ Ab)
{
    __shared__ float ddl[32 * DDS];   // 34.9 KB
    __shared__ float qst[32 * 64];    // 8 KB
    __shared__ float cst[32 * 64];    // 8 KB
    __shared__ float kcl[M_];
    __shared__ float rml[32], dil[32], dgl[32];

    const int tid = threadIdx.x;
    const int bh = blockIdx.y, b = bh >> 4, h = bh & 15;
    const int n0 = blockIdx.x * 128;

    float pr[64];
    if (tid < M_) {
        #pragma unroll
        for (int d = 0; d < 64; ++d) pr[d] = NORMC * proj[tid * 64 + d];
        kcl[tid] = kcs[(size_t)bh * M_ + tid];
    }

    for (int t0 = 0; t0 < 128; t0 += 32) {
        __syncthreads();
        // P1: stage q rows (fp32) + diag
        for (int idx = tid; idx < 32 * 64; idx += 320) {
            const int r = idx >> 6, d = idx & 63;
            qst[idx] = b2f(Qb[((size_t)b * N_ + n0 + t0 + r) * DIM_ + h * 64 + d]);
        }
        if (tid < 32) dgl[tid] = diagQ[((size_t)b * N_ + n0 + t0 + tid) * H_ + h];
        __syncthreads();
        // P2: dd tile
        if (tid < M_) {
            for (int r = 0; r < 32; ++r) {
                const float4* q4 = (const float4*)&qst[r * 64];
                float dd = 0.f;
                #pragma unroll
                for (int i = 0; i < 16; ++i) {
                    const float4 qv = q4[i];
                    dd += qv.x * pr[4*i] + qv.y * pr[4*i+1] + qv.z * pr[4*i+2] + qv.w * pr[4*i+3];
                }
                ddl[r * DDS + tid] = dd;
            }
        }
        __syncthreads();
        // P3: rowmax (8 lanes per row)
        if (tid < 256) {
            const int r = tid >> 3, p = tid & 7;
            float m = -3.4e38f;
            for (int mm = p; mm < M_; mm += 8) m = fmaxf(m, ddl[r * DDS + mm]);
            #pragma unroll
            for (int o = 4; o > 0; o >>= 1) m = fmaxf(m, __shfl_down(m, o, 8));
            if (p == 0) rml[r] = m;
        }
        __syncthreads();
        // P4: qp = ratio*(exp(dd - diag - rowmax) + eps), in place
        for (int idx = tid; idx < 32 * M_; idx += 320) {
            const int r = idx / M_;
            const int mm = idx - r * M_;
            ddl[r * DDS + mm] =
                RATIOC * (__expf(fminf(ddl[r * DDS + mm] - dgl[r] - rml[r], 0.f)) + EPSC);
        }
        __syncthreads();
        // den = qp . kcs  -> store 1/den
        if (tid < 256) {
            const int r = tid >> 3, p = tid & 7;
            float s = 0.f;
            for (int mm = p; mm < M_; mm += 8) s += ddl[r * DDS + mm] * kcl[mm];
            #pragma unroll
            for (int o = 4; o > 0; o >>= 1) s += __shfl_down(s, o, 8);
            if (p == 0) dil[r] = 1.0f / fmaxf(s, 1e-30f);
        }
        __syncthreads();
        // P5: out tile = qp @ context   (2 rows x 4 cols per thread)
        float acc2[2][4] = {};
        const int r0l = (tid >> 4) * 2, e0 = (tid & 15) * 4;
        for (int mb = 0; mb < M_; mb += 32) {
            const int cnt = (M_ - mb < 32) ? (M_ - mb) : 32;
            for (int idx = tid; idx < cnt * 64; idx += 320) {
                const int mm = idx >> 6, e = idx & 63;
                cst[idx] = ctx[((size_t)bh * M_ + mb + mm) * 64 + e];
            }
            __syncthreads();
            if (tid < 256) {
                for (int mm = 0; mm < cnt; ++mm) {
                    const float a0 = ddl[(r0l + 0) * DDS + mb + mm];
                    const float a1 = ddl[(r0l + 1) * DDS + mb + mm];
                    const float4 bv = *(const float4*)&cst[mm * 64 + e0];
                    acc2[0][0] += a0 * bv.x; acc2[0][1] += a0 * bv.y;
                    acc2[0][2] += a0 * bv.z; acc2[0][3] += a0 * bv.w;
                    acc2[1][0] += a1 * bv.x; acc2[1][1] += a1 * bv.y;
                    acc2[1][2] += a1 * bv.z; acc2[1][3] += a1 * bv.w;
                }
            }
            __syncthreads();
        }
        // P6: scale by D_inv and write attn (bf16)
        if (tid < 256) {
            #pragma unroll
            for (int i = 0; i < 2; ++i) {
                const float di = dil[r0l + i];
                const size_t row = (size_t)b * N_ + n0 + t0 + r0l + i;
                #pragma unroll
                for (int j = 0; j < 4; ++j)
                    Ab[row * DIM_ + h * 64 + e0 + j] = f2b(acc2[i][j] * di);
            }
        }
    }
}

// ---------------------------------------------------------------------------
extern "C" void kernel_launch(void* const* d_in, const int* in_sizes, int n_in,
                              void* d_out, int out_size, void* d_ws, size_t ws_size,
                              hipStream_t stream)
{
    const float* x    = (const float*)d_in[0];
    const float* Wq   = (const float*)d_in[1];
    const float* Wk   = (const float*)d_in[2];
    const float* Wv   = (const float*)d_in[3];
    const float* Wo   = (const float*)d_in[4];
    const float* bo   = (const float*)d_in[5];
    const float* proj = (const float*)d_in[6];

    char* ws = (char*)d_ws;
    size_t o = 0;
    __hip_bfloat16* Qb = (__hip_bfloat16*)(ws + o); o += (size_t)RT_ * DIM_ * 2;
    __hip_bfloat16* Kb = (__hip_bfloat16*)(ws + o); o += (size_t)RT_ * DIM_ * 2;
    __hip_bfloat16* Vb = (__hip_bfloat16*)(ws + o); o += (size_t)RT_ * DIM_ * 2;
    __hip_bfloat16* Ab = (__hip_bfloat16*)(ws + o); o += (size_t)RT_ * DIM_ * 2;
    float*    ctx   = (float*)(ws + o);    o += (size_t)BH_ * M_ * 64 * 4;
    float*    kcs   = (float*)(ws + o);    o += (size_t)BH_ * M_ * 4;
    unsigned* kmaxb = (unsigned*)(ws + o); o += 128;
    float*    diagQ = (float*)(ws + o);    o += (size_t)RT_ * H_ * 4;
    float*    diagK = (float*)(ws + o);    o += (size_t)RT_ * H_ * 4;

    // zero ctx + kcs + kmaxb (contiguous; ws is poisoned 0xAA each call)
    const size_t zbytes = (size_t)BH_ * M_ * 64 * 4 + (size_t)BH_ * M_ * 4 + 128;
    hipMemsetAsync(ctx, 0, zbytes, stream);

    const dim3 gblk(256), ggrid(DIM_ / 64, RT_ / 64);
    gemm_tn<true,  false><<<ggrid, gblk, 0, stream>>>(x, Wq, (const float*)nullptr, Qb, diagQ);
    gemm_tn<true,  false><<<ggrid, gblk, 0, stream>>>(x, Wk, (const float*)nullptr, Kb, diagK);
    gemm_tn<false, false><<<ggrid, gblk, 0, stream>>>(x, Wv, (const float*)nullptr, Vb, nullptr);

    kmax_kernel<<<dim3(8, BH_), 320, 0, stream>>>(Kb, proj, kmaxb);
    kctx_kernel<<<dim3(8, BH_), 320, 0, stream>>>(Kb, Vb, proj, diagK, kmaxb, ctx, kcs);
    qout_kernel<<<dim3(N_ / 128, BH_), 320, 0, stream>>>(Qb, proj, diagQ, ctx, kcs, Ab);

    gemm_tn<false, true><<<ggrid, gblk, 0, stream>>>(Ab, Wo, bo, (float*)d_out, nullptr);
}